// Round 10
// baseline (131.569 us; speedup 1.0000x reference)
//
#include <hip/hip_runtime.h>

#define IMG_H 512
#define IMG_W 512
#define IMGSZ (IMG_H * IMG_W)
#define NIMG 48                       // B*C
#define NB 16
#define NPOS 4096
#define DNPIX 12582912.0              // 48*512*512

#define RB 4                          // rows per band (one wave per band)
#define WPB 4                         // waves per block, vertically adjacent
#define BLOCK_ROWS (RB * WPB)         // 16
#define BGRPS (IMG_H / BLOCK_ROWS)    // 32 block-bands per image
#define SSIM_BLOCKS (NIMG * BGRPS)    // 1536 (divisible by 8; 6 per CU)
#define TOTAL_BLOCKS SSIM_BLOCKS

__device__ __forceinline__ float ssim_val(float Sx, float Sy, float Sxx,
                                          float Syy, float Sxy)
{
    const float inv121 = 1.0f / 121.0f;
    const float C1c = 1e-4f, C2c = 9e-4f;
    float mux = Sx * inv121, muy = Sy * inv121;
    float sgx = Sxx * inv121 - mux * mux;
    float sgy = Syy * inv121 - muy * muy;
    float sgxy = Sxy * inv121 - mux * muy;
    float num = (2.f * mux * muy + C1c) * (2.f * sgxy + C2c);
    float den = (mux * mux + muy * muy + C1c) * (sgx + sgy + C2c);
    return __fdividef(num, den);
}

__device__ __forceinline__ void load8(const float* __restrict__ base, float x[8])
{
    const float4* p = (const float4*)base;
    float4 a = p[0], b = p[1];
    x[0] = a.x; x[1] = a.y; x[2] = a.z; x[3] = a.w;
    x[4] = b.x; x[5] = b.y; x[6] = b.z; x[7] = b.w;
}

// Horizontal 11-tap window sums across lane-owned 8-col segments via shfl,
// then SSIM for the 8 output columns of this lane. No LDS, no bank conflicts.
__device__ __forceinline__ float horiz_ssim(const float V[5][8], int lane)
{
    float W[5][8];
#pragma unroll
    for (int q = 0; q < 5; ++q) {
        float A0 = V[q][0];
        float A1 = A0 + V[q][1];
        float A2 = A1 + V[q][2];
        float A3 = A2 + V[q][3];
        float A4 = A3 + V[q][4];
        float A5 = A4 + V[q][5];
        float A6 = A5 + V[q][6];
        float T  = A6 + V[q][7];
        float B1 = T - A0, B2 = T - A1, B3 = T - A2, B4 = T - A3;
        float B5 = T - A4, B6 = T - A5, B7 = T - A6;
        float LB3 = __shfl_up(B3, 1), LB4 = __shfl_up(B4, 1);
        float LB5 = __shfl_up(B5, 1), LB6 = __shfl_up(B6, 1);
        float LB7 = __shfl_up(B7, 1);
        float RA0 = __shfl_down(A0, 1), RA1 = __shfl_down(A1, 1);
        float RA2 = __shfl_down(A2, 1), RA3 = __shfl_down(A3, 1);
        float RA4 = __shfl_down(A4, 1);
        if (lane == 0)  { LB3 = LB4 = LB5 = LB6 = LB7 = 0.f; }  // cols <0 are 0
        if (lane == 63) { RA0 = RA1 = RA2 = RA3 = RA4 = 0.f; }  // cols >=512 are 0
        W[q][0] = LB3 + A5;
        W[q][1] = LB4 + A6;
        W[q][2] = LB5 + T;
        W[q][3] = LB6 + T + RA0;
        W[q][4] = LB7 + T + RA1;
        W[q][5] = T + RA2;
        W[q][6] = B1 + RA3;
        W[q][7] = B2 + RA4;
    }
    float s = 0.f;
#pragma unroll
    for (int j = 0; j < 8; ++j)
        s += ssim_val(W[0][j], W[1][j], W[2][j], W[3][j], W[4][j]);
    return s;
}

__global__ __launch_bounds__(256) void fused_kernel(
    const float* __restrict__ pred, const float* __restrict__ targ,
    const int* __restrict__ pos32, const float* __restrict__ imp,
    double* __restrict__ acc, unsigned int* __restrict__ cnt,
    float* __restrict__ out)
{
    const int tid = threadIdx.x;
    const int lane = tid & 63;
    const int wid = tid >> 6;
    const int bid = blockIdx.x;
    float ssim_s = 0.f, perc = 0.f, samp = 0.f;

    // ---------------- SSIM + perceptual (every wave owns a 4-row band) ----
    // bijective XCD swizzle: same-XCD blocks cover contiguous bands
    int s = (bid & 7) * (SSIM_BLOCKS / 8) + (bid >> 3);
    const int img = s >> 5;            // BGRPS == 32
    const int bg = s & 31;
    const int rs = bg * BLOCK_ROWS + wid * RB;   // this wave's 4-row band
    const float* __restrict__ pimg = pred + (size_t)img * IMGSZ;
    const float* __restrict__ timg = targ + (size_t)img * IMGSZ;
    const int c0 = lane * 8;

    float V[5][8];
#pragma unroll
    for (int q = 0; q < 5; ++q)
#pragma unroll
        for (int k = 0; k < 8; ++k) V[q][k] = 0.f;

    // warm-up rows rs-5 .. rs+5 — branch-free: clamp row, mask values
    for (int kk = 0; kk < 11; ++kk) {
        int gr = rs - 5 + kk;
        int gc = min(max(gr, 0), IMG_H - 1);       // clamped, always valid
        float m = (gr == gc) ? 1.f : 0.f;          // 0 outside image
        float x[8], y[8];
        load8(pimg + (size_t)gc * IMG_W + c0, x);
        load8(timg + (size_t)gc * IMG_W + c0, y);
        bool pin = (gr >= rs) && (gr < rs + RB);   // in-band rows, counted once
#pragma unroll
        for (int k = 0; k < 8; ++k) {
            float xv = x[k] * m, yv = y[k] * m;
            V[0][k] += xv;
            V[1][k] += yv;
            V[2][k] = fmaf(xv, xv, V[2][k]);
            V[3][k] = fmaf(yv, yv, V[3][k]);
            V[4][k] = fmaf(xv, yv, V[4][k]);
            perc += pin ? fabsf(xv - yv) : 0.f;
        }
    }
    ssim_s += horiz_ssim(V, lane);

    // stream down the band — branch-free loads (entering rows never in-band)
    for (int r = 1; r < RB; ++r) {
        int ge = rs + r + 5;            // entering row
        int gl = rs + r - 6;            // leaving row
        int gec = min(ge, IMG_H - 1);
        int glc = max(gl, 0);
        float me = (ge == gec) ? 1.f : 0.f;
        float ml = (gl == glc) ? 1.f : 0.f;
        float xe[8], ye[8], xl[8], yl[8];
        load8(pimg + (size_t)gec * IMG_W + c0, xe);
        load8(timg + (size_t)gec * IMG_W + c0, ye);
        load8(pimg + (size_t)glc * IMG_W + c0, xl);
        load8(timg + (size_t)glc * IMG_W + c0, yl);
#pragma unroll
        for (int k = 0; k < 8; ++k) {
            float xev = xe[k] * me, yev = ye[k] * me;
            float xlv = xl[k] * ml, ylv = yl[k] * ml;
            V[0][k] += xev - xlv;
            V[1][k] += yev - ylv;
            V[2][k] += fmaf(xev, xev, -xlv * xlv);
            V[3][k] += fmaf(yev, yev, -ylv * ylv);
            V[4][k] += fmaf(xev, yev, -xlv * ylv);
        }
        ssim_s += horiz_ssim(V, lane);
    }

    // ---------------- sampled loss, spread over all blocks/waves ----------
    // block bid owns samples [bid*NPOS/SSIM_BLOCKS, ...) — 2 or 3 of them;
    // wave w handles one sample; 64 lanes cooperate (48 pixels + 16 weights).
    {
        int n0 = (bid * NPOS) / SSIM_BLOCKS;
        int n1 = ((bid + 1) * NPOS) / SSIM_BLOCKS;
        if (wid < n1 - n0) {
            int n = n0 + wid;
            // layout probe: first 64 odd 32-bit words all zero <=> int64
            unsigned long long ball = __ballot(pos32[2 * lane + 1] != 0);
            int u, v;
            if (ball == 0ull) { u = pos32[4 * n]; v = pos32[4 * n + 2]; }
            else              { u = pos32[2 * n]; v = pos32[2 * n + 1]; }
            int off = u * IMG_W + v;
            float a = 0.f, w = 0.f;
            if (lane < NIMG) {
                float d = pred[(size_t)lane * IMGSZ + off]
                        - targ[(size_t)lane * IMGSZ + off];
                a = d * d;
            } else {
                w = 1.0f / (imp[(size_t)(lane - NIMG) * IMGSZ + off] + 0.1f);
            }
#pragma unroll
            for (int o = 32; o > 0; o >>= 1) {
                a += __shfl_down(a, o);
                w += __shfl_down(w, o);
            }
            if (lane == 0)
                samp = (w * (1.0f / 16.0f)) * (a * (1.0f / 48.0f));
        }
    }

    // ---------------- reduction: wave -> block -> atomics ----------------
#pragma unroll
    for (int o = 32; o > 0; o >>= 1) {
        ssim_s += __shfl_down(ssim_s, o);
        perc   += __shfl_down(perc, o);
    }
    __shared__ float red[3][WPB];
    if (lane == 0) { red[0][wid] = ssim_s; red[1][wid] = perc; red[2][wid] = samp; }
    __syncthreads();
    if (tid == 0) {
        float ss = 0.f, pp = 0.f, mm = 0.f;
#pragma unroll
        for (int k = 0; k < WPB; ++k) {
            ss += red[0][k]; pp += red[1][k]; mm += red[2][k];
        }
        atomicAdd(&acc[0], (double)ss);
        atomicAdd(&acc[1], (double)pp);
        atomicAdd(&acc[2], (double)mm);
        __threadfence();
        unsigned int old = atomicAdd(cnt, 1u);
        if (old == TOTAL_BLOCKS - 1) {
            double s0 = atomicAdd(&acc[0], 0.0);
            double s1 = atomicAdd(&acc[1], 0.0);
            double s2 = atomicAdd(&acc[2], 0.0);
            double sampled = s2 / (double)NPOS;
            double perceptual = s1 / DNPIX;
            double structural = 1.0 - s0 / DNPIX;
            double total = 0.3 * sampled + 0.4 * perceptual + 0.2 * structural;
            out[0] = (float)total;
            out[1] = (float)sampled;
            out[2] = (float)perceptual;
            out[3] = (float)structural;
            out[4] = 0.0f;
        }
    }
}

extern "C" void kernel_launch(void* const* d_in, const int* in_sizes, int n_in,
                              void* d_out, int out_size, void* d_ws, size_t ws_size,
                              hipStream_t stream)
{
    const float* pred = (const float*)d_in[0];
    const float* targ = (const float*)d_in[1];
    const int* pos = (const int*)d_in[2];
    const float* imp = (const float*)d_in[3];
    float* out = (float*)d_out;
    double* acc = (double*)d_ws;                       // acc[0..2]
    unsigned int* cnt = (unsigned int*)((char*)d_ws + 24);

    hipMemsetAsync(d_ws, 0, 32, stream);
    hipLaunchKernelGGL(fused_kernel, dim3(TOTAL_BLOCKS), dim3(256), 0, stream,
                       pred, targ, pos, imp, acc, cnt, out);
}

// Round 12
// 94.270 us; speedup vs baseline: 1.3957x; 1.3957x over previous
//
#include <hip/hip_runtime.h>

#define IMG_H 512
#define IMG_W 512
#define IMGSZ (IMG_H * IMG_W)
#define NIMG 48                       // B*C
#define NB 16
#define NPOS 4096
#define DNPIX 12582912.0              // 48*512*512

#define RB 8                          // rows per band (one wave per band)
#define WPB 4                         // waves per block, vertically adjacent
#define BLOCK_ROWS (RB * WPB)         // 32
#define BGRPS (IMG_H / BLOCK_ROWS)    // 16 block-bands per image
#define SSIM_BLOCKS (NIMG * BGRPS)    // 768 = exactly 3 blocks per CU, no tail
#define TOTAL_BLOCKS SSIM_BLOCKS

__device__ __forceinline__ float ssim_val(float Sx, float Sy, float Sxx,
                                          float Syy, float Sxy)
{
    const float inv121 = 1.0f / 121.0f;
    const float C1c = 1e-4f, C2c = 9e-4f;
    float mux = Sx * inv121, muy = Sy * inv121;
    float sgx = Sxx * inv121 - mux * mux;
    float sgy = Syy * inv121 - muy * muy;
    float sgxy = Sxy * inv121 - mux * muy;
    float num = (2.f * mux * muy + C1c) * (2.f * sgxy + C2c);
    float den = (mux * mux + muy * muy + C1c) * (sgx + sgy + C2c);
    return __fdividef(num, den);
}

__device__ __forceinline__ void load8(const float* __restrict__ base, float x[8])
{
    const float4* p = (const float4*)base;
    float4 a = p[0], b = p[1];
    x[0] = a.x; x[1] = a.y; x[2] = a.z; x[3] = a.w;
    x[4] = b.x; x[5] = b.y; x[6] = b.z; x[7] = b.w;
}

// Horizontal 11-tap window sums across lane-owned 8-col segments via shfl,
// then SSIM for the 8 output columns of this lane. No LDS, no bank conflicts.
__device__ __forceinline__ float horiz_ssim(const float V[5][8], int lane)
{
    float W[5][8];
#pragma unroll
    for (int q = 0; q < 5; ++q) {
        float A0 = V[q][0];
        float A1 = A0 + V[q][1];
        float A2 = A1 + V[q][2];
        float A3 = A2 + V[q][3];
        float A4 = A3 + V[q][4];
        float A5 = A4 + V[q][5];
        float A6 = A5 + V[q][6];
        float T  = A6 + V[q][7];
        float B1 = T - A0, B2 = T - A1, B3 = T - A2, B4 = T - A3;
        float B5 = T - A4, B6 = T - A5, B7 = T - A6;
        float LB3 = __shfl_up(B3, 1), LB4 = __shfl_up(B4, 1);
        float LB5 = __shfl_up(B5, 1), LB6 = __shfl_up(B6, 1);
        float LB7 = __shfl_up(B7, 1);
        float RA0 = __shfl_down(A0, 1), RA1 = __shfl_down(A1, 1);
        float RA2 = __shfl_down(A2, 1), RA3 = __shfl_down(A3, 1);
        float RA4 = __shfl_down(A4, 1);
        if (lane == 0)  { LB3 = LB4 = LB5 = LB6 = LB7 = 0.f; }  // cols <0 are 0
        if (lane == 63) { RA0 = RA1 = RA2 = RA3 = RA4 = 0.f; }  // cols >=512 are 0
        W[q][0] = LB3 + A5;
        W[q][1] = LB4 + A6;
        W[q][2] = LB5 + T;
        W[q][3] = LB6 + T + RA0;
        W[q][4] = LB7 + T + RA1;
        W[q][5] = T + RA2;
        W[q][6] = B1 + RA3;
        W[q][7] = B2 + RA4;
    }
    float s = 0.f;
#pragma unroll
    for (int j = 0; j < 8; ++j)
        s += ssim_val(W[0][j], W[1][j], W[2][j], W[3][j], W[4][j]);
    return s;
}

__global__ __launch_bounds__(256) void fused_kernel(
    const float* __restrict__ pred, const float* __restrict__ targ,
    const int* __restrict__ pos32, const float* __restrict__ imp,
    double* __restrict__ acc, unsigned int* __restrict__ cnt,
    float* __restrict__ out)
{
    const int tid = threadIdx.x;
    const int lane = tid & 63;
    const int wid = tid >> 6;
    const int bid = blockIdx.x;
    float ssim_s = 0.f, perc = 0.f, samp = 0.f;

    // ---------------- SSIM + perceptual (every wave owns an 8-row band) ----
    // bijective XCD swizzle: same-XCD blocks cover contiguous bands
    int s = (bid & 7) * (SSIM_BLOCKS / 8) + (bid >> 3);
    const int img = s >> 4;            // BGRPS == 16
    const int bg = s & 15;
    const int rs = bg * BLOCK_ROWS + wid * RB;   // this wave's 8-row band
    const float* __restrict__ pimg = pred + (size_t)img * IMGSZ;
    const float* __restrict__ timg = targ + (size_t)img * IMGSZ;
    const int c0 = lane * 8;

    float V[5][8];
#pragma unroll
    for (int q = 0; q < 5; ++q)
#pragma unroll
        for (int k = 0; k < 8; ++k) V[q][k] = 0.f;

    // warm-up rows rs-5 .. rs+5 — branch-free: clamp row, mask values
    for (int kk = 0; kk < 11; ++kk) {
        int gr = rs - 5 + kk;
        int gc = min(max(gr, 0), IMG_H - 1);
        float m = (gr == gc) ? 1.f : 0.f;          // 0 outside image
        float x[8], y[8];
        load8(pimg + (size_t)gc * IMG_W + c0, x);
        load8(timg + (size_t)gc * IMG_W + c0, y);
        bool pin = (gr >= rs);                     // gr<=rs+5<rs+RB: in-band
#pragma unroll
        for (int k = 0; k < 8; ++k) {
            float xv = x[k] * m, yv = y[k] * m;
            V[0][k] += xv;
            V[1][k] += yv;
            V[2][k] = fmaf(xv, xv, V[2][k]);
            V[3][k] = fmaf(yv, yv, V[3][k]);
            V[4][k] = fmaf(xv, yv, V[4][k]);
            perc += pin ? fabsf(xv - yv) : 0.f;
        }
    }
    ssim_s += horiz_ssim(V, lane);

    // ---- software-pipelined stream: carried raw rows + masks, loads issued
    //      one step ahead so HBM latency hides under horiz_ssim ----
    float xe[8], ye[8], xl[8], yl[8];
    float me, ml;
    {
        int ge = rs + 6, gl = rs - 5;
        int gec = min(ge, IMG_H - 1);   // ge >= 6, no lower clamp needed
        int glc = max(gl, 0);           // gl <= 499, no upper clamp needed
        me = (ge == gec) ? 1.f : 0.f;
        ml = (gl == glc) ? 1.f : 0.f;
        load8(pimg + (size_t)gec * IMG_W + c0, xe);
        load8(timg + (size_t)gec * IMG_W + c0, ye);
        load8(pimg + (size_t)glc * IMG_W + c0, xl);
        load8(timg + (size_t)glc * IMG_W + c0, yl);
    }
    for (int r = 1; r < RB; ++r) {
        // (1) V-update consumes the carried rows
        float cme = me, cml = ml;
        bool pin = (r < 3);             // entering rows rs+6, rs+7 are in-band
#pragma unroll
        for (int k = 0; k < 8; ++k) {
            float a = xe[k] * cme, b = ye[k] * cme;
            float c = xl[k] * cml, d = yl[k] * cml;
            V[0][k] += a - c;
            V[1][k] += b - d;
            V[2][k] += fmaf(a, a, -c * c);
            V[3][k] += fmaf(b, b, -d * d);
            V[4][k] += fmaf(a, b, -c * d);
            perc += pin ? fabsf(a - b) : 0.f;
        }
        // (2) issue next step's loads (unconditional; dummy at r==RB-1)
        int ge2 = rs + r + 6, gl2 = rs + r - 5;
        int gec = min(ge2, IMG_H - 1);  // ge2 >= rs+7 > 0
        int glc = max(gl2, 0);          // gl2 <= rs+RB-5+1 <= 508 < 512
        me = (ge2 == gec) ? 1.f : 0.f;
        ml = (gl2 == glc) ? 1.f : 0.f;
        load8(pimg + (size_t)gec * IMG_W + c0, xe);
        load8(timg + (size_t)gec * IMG_W + c0, ye);
        load8(pimg + (size_t)glc * IMG_W + c0, xl);
        load8(timg + (size_t)glc * IMG_W + c0, yl);
        // (3) horiz + ssim while loads are in flight
        ssim_s += horiz_ssim(V, lane);
    }

    // ---------------- sampled loss, spread over all blocks/waves ----------
    // block bid owns samples [bid*NPOS/768, (bid+1)*NPOS/768) — 5 or 6;
    // wave w handles samples n0+w, n0+w+4, ...; 64 lanes cooperate on one.
    {
        int n0 = (bid * NPOS) / SSIM_BLOCKS;
        int n1 = ((bid + 1) * NPOS) / SSIM_BLOCKS;
        // layout probe once: first 64 odd 32-bit words all zero <=> int64
        unsigned long long ball = __ballot(pos32[2 * lane + 1] != 0);
        for (int n = n0 + wid; n < n1; n += WPB) {
            int u, v;
            if (ball == 0ull) { u = pos32[4 * n]; v = pos32[4 * n + 2]; }
            else              { u = pos32[2 * n]; v = pos32[2 * n + 1]; }
            int off = u * IMG_W + v;
            float a = 0.f, w = 0.f;
            if (lane < NIMG) {
                float d = pred[(size_t)lane * IMGSZ + off]
                        - targ[(size_t)lane * IMGSZ + off];
                a = d * d;
            } else {
                w = 1.0f / (imp[(size_t)(lane - NIMG) * IMGSZ + off] + 0.1f);
            }
#pragma unroll
            for (int o = 32; o > 0; o >>= 1) {
                a += __shfl_down(a, o);
                w += __shfl_down(w, o);
            }
            if (lane == 0)
                samp += (w * (1.0f / 16.0f)) * (a * (1.0f / 48.0f));
        }
    }

    // ---------------- reduction: wave -> block -> atomics ----------------
#pragma unroll
    for (int o = 32; o > 0; o >>= 1) {
        ssim_s += __shfl_down(ssim_s, o);
        perc   += __shfl_down(perc, o);
    }
    __shared__ float red[3][WPB];
    if (lane == 0) { red[0][wid] = ssim_s; red[1][wid] = perc; red[2][wid] = samp; }
    __syncthreads();
    if (tid == 0) {
        float ss = 0.f, pp = 0.f, mm = 0.f;
#pragma unroll
        for (int k = 0; k < WPB; ++k) {
            ss += red[0][k]; pp += red[1][k]; mm += red[2][k];
        }
        atomicAdd(&acc[0], (double)ss);
        atomicAdd(&acc[1], (double)pp);
        atomicAdd(&acc[2], (double)mm);
        __threadfence();
        unsigned int old = atomicAdd(cnt, 1u);
        if (old == TOTAL_BLOCKS - 1) {
            double s0 = atomicAdd(&acc[0], 0.0);
            double s1 = atomicAdd(&acc[1], 0.0);
            double s2 = atomicAdd(&acc[2], 0.0);
            double sampled = s2 / (double)NPOS;
            double perceptual = s1 / DNPIX;
            double structural = 1.0 - s0 / DNPIX;
            double total = 0.3 * sampled + 0.4 * perceptual + 0.2 * structural;
            out[0] = (float)total;
            out[1] = (float)sampled;
            out[2] = (float)perceptual;
            out[3] = (float)structural;
            out[4] = 0.0f;
        }
    }
}

extern "C" void kernel_launch(void* const* d_in, const int* in_sizes, int n_in,
                              void* d_out, int out_size, void* d_ws, size_t ws_size,
                              hipStream_t stream)
{
    const float* pred = (const float*)d_in[0];
    const float* targ = (const float*)d_in[1];
    const int* pos = (const int*)d_in[2];
    const float* imp = (const float*)d_in[3];
    float* out = (float*)d_out;
    double* acc = (double*)d_ws;                       // acc[0..2]
    unsigned int* cnt = (unsigned int*)((char*)d_ws + 24);

    hipMemsetAsync(d_ws, 0, 32, stream);
    hipLaunchKernelGGL(fused_kernel, dim3(TOTAL_BLOCKS), dim3(256), 0, stream,
                       pred, targ, pos, imp, acc, cnt, out);
}